// Round 1
// 964.371 us; speedup vs baseline: 1.0509x; 1.0509x over previous
//
#include <hip/hip_runtime.h>
#include <math.h>

#define DIM 128
#define BATCH 1048576
#define WT_STRIDE 136   // bf16 elements per row of W^T: 128 + 8 pad
#define VT_STRIDE 132   // f32 stride for staged v columns: %4==0 -> 16B-aligned b128 reads
#define GEMM_GRID 512   // 2 blocks per CU, fully persistent
#define NTILES (BATCH / 128)            // 8192
#define TILES_PER_BLOCK (NTILES / GEMM_GRID)  // 16 (even -> clean ping-pong)

typedef float f32x4 __attribute__((ext_vector_type(4)));
typedef short bf16x8 __attribute__((ext_vector_type(8)));

// fp32 -> bf16 round-to-nearest-even (bit trick; no NaN inputs here)
__device__ __forceinline__ unsigned short f2bf(float f) {
    unsigned u = __builtin_bit_cast(unsigned, f);
    u += 0x7FFFu + ((u >> 16) & 1u);
    return (unsigned short)(u >> 16);
}

// ---------------------------------------------------------------------------
// Kernel A: build W^T (bf16, padded stride) from the Householder scan.
// Single block, 256 threads. Pair-per-row layout: thread t holds
// Q[r][c0..c0+63], r = t>>1, c0 = (t&1)*64 -> the row dot is a single
// __shfl_xor(dot,1). Norm computed redundantly in every wave (butterfly).
// ZERO barriers inside the 128-step loop (v is read-only LDS, q is
// thread-local, coef comes from a lane-pair shuffle).
// ---------------------------------------------------------------------------
__global__ __launch_bounds__(256, 1) void build_w_kernel(
    const float* __restrict__ vvec,     // [128][128], v_i = column i
    const float* __restrict__ scale_p,  // [1]
    const float* __restrict__ diag,     // [128]
    unsigned short* __restrict__ wt,    // [128][WT_STRIDE] bf16: wt[c][r] = W[r][c]
    float* __restrict__ logdet_out)
{
    __shared__ float vt[DIM * VT_STRIDE];   // vt[i*132 + j] = v_i[j]

    const int t    = threadIdx.x;
    const int r    = t >> 1;
    const int c0   = (t & 1) * 64;
    const int lane = t & 63;

    // load + transpose v_vectors (coalesced global read; LDS-write 8-way
    // conflict on stride 132 is paid exactly once -> irrelevant)
    for (int idx = t; idx < DIM * DIM; idx += 256) {
        int j = idx >> 7;      // row of vvec
        int i = idx & 127;     // col of vvec == step index
        vt[i * VT_STRIDE + j] = vvec[idx];
    }

    // Q = I  (compile-time indices only -> stays in VGPRs)
    float q[64];
    #pragma unroll
    for (int j = 0; j < 64; ++j) q[j] = (c0 + j == r) ? 1.0f : 0.0f;

    __syncthreads();   // the ONLY barrier the scan needs

    for (int i = 0; i < DIM; ++i) {
        const float* __restrict__ v = &vt[i * VT_STRIDE];

        // redundant per-wave norm: 2 loads + butterfly, all 64 lanes end
        // with the same sc (no LDS broadcast, no barrier)
        float na = v[lane], nb = v[lane + 64];
        float ss = na * na + nb * nb;
        #pragma unroll
        for (int m = 32; m >= 1; m >>= 1) ss += __shfl_xor(ss, m, 64);
        const float sc = 1.0f / (sqrtf(ss) + 1e-8f);

        // pull this thread's 64 v elements into registers once (b128 reads,
        // 2 distinct broadcast addresses per instr -> conflict-free);
        // reused by both the dot and the update.
        float vv[64];
        #pragma unroll
        for (int k = 0; k < 16; ++k) {
            f32x4 w = *(const f32x4*)(v + c0 + 4 * k);
            vv[4*k]   = w[0]; vv[4*k+1] = w[1];
            vv[4*k+2] = w[2]; vv[4*k+3] = w[3];
        }

        // partial dot with 4 accumulators (cuts the serial FMA chain 4x)
        float d0 = 0.f, d1 = 0.f, d2 = 0.f, d3 = 0.f;
        #pragma unroll
        for (int k = 0; k < 16; ++k) {
            d0 += q[4*k]   * vv[4*k];
            d1 += q[4*k+1] * vv[4*k+1];
            d2 += q[4*k+2] * vv[4*k+2];
            d3 += q[4*k+3] * vv[4*k+3];
        }
        float dot = (d0 + d1) + (d2 + d3);
        dot += __shfl_xor(dot, 1, 64);   // lane pair (t, t^1) share row r

        // Q[r][c] -= 2*sc^2 * (Q.v_raw)[r] * v_raw[c]
        const float coef = 2.0f * sc * sc * dot;
        #pragma unroll
        for (int j = 0; j < 64; ++j) q[j] -= coef * vv[j];
    }

    // W[r][c] = Q[r][c] * diag[c] * s ; store transposed bf16
    const float s = scale_p[0];
    #pragma unroll
    for (int j = 0; j < 64; ++j) {
        const int c = c0 + j;
        wt[c * WT_STRIDE + r] = f2bf(q[j] * diag[c] * s);
    }

    // logdet: wave 0, butterfly reduce (was a serial 128-iter loop on t==0)
    if (t < 64) {
        float ld = logf(fabsf(diag[t] * s) + 1e-8f)
                 + logf(fabsf(diag[t + 64] * s) + 1e-8f);
        #pragma unroll
        for (int m = 32; m >= 1; m >>= 1) ld += __shfl_xor(ld, m, 64);
        if (t == 0) *logdet_out = ld;
    }
}

// ---------------------------------------------------------------------------
// Kernel B: y = x @ W. Persistent: 512 blocks (2/CU), each grid-strides 16
// tiles of 128 rows. W^T staged to LDS ONCE per block. Cross-tile ping-pong
// double-buffer of x registers (xa/xb, all static indexing) keeps the next
// tile's 16 dwordx4 loads in flight under the current tile's MFMA + stores.
// ---------------------------------------------------------------------------
__global__ __launch_bounds__(256, 2) void gemm_kernel(
    const float* __restrict__ x,
    const unsigned short* __restrict__ wt,
    float* __restrict__ y)
{
    __shared__ unsigned short wlds[DIM * WT_STRIDE];   // 34816 B

    const int t = threadIdx.x;

    // stage W^T into LDS (16B chunks; pad bytes copied but never used)
    const int total4 = DIM * WT_STRIDE / 8;   // 2176
    for (int idx = t; idx < total4; idx += 256) {
        ((f32x4*)wlds)[idx] = ((const f32x4*)wt)[idx];
    }

    const int wave = t >> 6;
    const int lane = t & 63;
    const int n15  = lane & 15;
    const int quad = lane >> 4;

    // issue x loads for one tile into a register buffer
    auto loadx = [&](f32x4 (&xb)[2][8], int tileIdx) {
        const long rowbase = (long)tileIdx * 128 + wave * 32;
        #pragma unroll
        for (int rt = 0; rt < 2; ++rt) {
            const float* xrow = x + (rowbase + rt * 16 + n15) * DIM + quad * 8;
            #pragma unroll
            for (int kc = 0; kc < 4; ++kc) {
                xb[rt][kc * 2]     = *(const f32x4*)(xrow + kc * 32);
                xb[rt][kc * 2 + 1] = *(const f32x4*)(xrow + kc * 32 + 4);
            }
        }
    };

    // convert + 64 MFMA + store one tile
    auto compute_store = [&](const f32x4 (&xb)[2][8], int tileIdx) {
        const long rowbase = (long)tileIdx * 128 + wave * 32;

        f32x4 acc[2][8];
        #pragma unroll
        for (int rt = 0; rt < 2; ++rt)
            #pragma unroll
            for (int ct = 0; ct < 8; ++ct)
                acc[rt][ct] = (f32x4)0.0f;

        #pragma unroll
        for (int kc = 0; kc < 4; ++kc) {
            bf16x8 afrag[2];
            #pragma unroll
            for (int rt = 0; rt < 2; ++rt) {
                const f32x4 lo = xb[rt][kc * 2];
                const f32x4 hi = xb[rt][kc * 2 + 1];
                bf16x8 f;
                f[0] = (short)f2bf(lo[0]); f[1] = (short)f2bf(lo[1]);
                f[2] = (short)f2bf(lo[2]); f[3] = (short)f2bf(lo[3]);
                f[4] = (short)f2bf(hi[0]); f[5] = (short)f2bf(hi[1]);
                f[6] = (short)f2bf(hi[2]); f[7] = (short)f2bf(hi[3]);
                afrag[rt] = f;
            }
            const int koff = kc * 32 + quad * 8;
            #pragma unroll
            for (int ct = 0; ct < 8; ++ct) {
                const bf16x8 bfrag = *(const bf16x8*)&wlds[(ct * 16 + n15) * WT_STRIDE + koff];
                acc[0][ct] = __builtin_amdgcn_mfma_f32_16x16x32_bf16(afrag[0], bfrag, acc[0][ct], 0, 0, 0);
                acc[1][ct] = __builtin_amdgcn_mfma_f32_16x16x32_bf16(afrag[1], bfrag, acc[1][ct], 0, 0, 0);
            }
        }

        // epilogue: C/D layout col = lane&15, row = quad*4 + reg.
        #pragma unroll
        for (int rt = 0; rt < 2; ++rt) {
            #pragma unroll
            for (int reg = 0; reg < 4; ++reg) {
                float* yrow = y + (rowbase + rt * 16 + quad * 4 + reg) * DIM;
                #pragma unroll
                for (int ct = 0; ct < 8; ++ct) {
                    yrow[ct * 16 + n15] = acc[rt][ct][reg];
                }
            }
        }
    };

    f32x4 xa[2][8], xb[2][8];

    loadx(xa, blockIdx.x);          // tile k=0 loads overlap the LDS staging
    __syncthreads();                // wlds ready

    for (int kk = 0; kk < TILES_PER_BLOCK / 2; ++kk) {
        const int t0 = blockIdx.x + (2 * kk)     * GEMM_GRID;
        const int t1 = blockIdx.x + (2 * kk + 1) * GEMM_GRID;
        loadx(xb, t1);              // in flight under compute of t0
        compute_store(xa, t0);
        if (kk + 1 < TILES_PER_BLOCK / 2)
            loadx(xa, blockIdx.x + (2 * kk + 2) * GEMM_GRID);  // under compute of t1
        compute_store(xb, t1);
    }
}

extern "C" void kernel_launch(void* const* d_in, const int* in_sizes, int n_in,
                              void* d_out, int out_size, void* d_ws, size_t ws_size,
                              hipStream_t stream) {
    const float* x     = (const float*)d_in[0];
    const float* vvec  = (const float*)d_in[1];
    const float* scale = (const float*)d_in[2];
    const float* diag  = (const float*)d_in[3];

    float* y = (float*)d_out;
    float* logdet = y + (size_t)BATCH * DIM;        // outputs concatenated: y then logdet
    unsigned short* wt = (unsigned short*)d_ws;     // needs 128*136*2 = 34816 B

    build_w_kernel<<<1, 256, 0, stream>>>(vvec, scale, diag, wt, logdet);
    gemm_kernel<<<GEMM_GRID, 256, 0, stream>>>(x, wt, y);
}